// Round 18
// baseline (163.044 us; speedup 1.0000x reference)
//
#include <hip/hip_runtime.h>
#include <math.h>

typedef _Float16 f16;
typedef _Float16 f16x2 __attribute__((ext_vector_type(2)));
typedef _Float16 f16x4 __attribute__((ext_vector_type(4)));
typedef _Float16 f16x8 __attribute__((ext_vector_type(8)));
typedef float f32x4 __attribute__((ext_vector_type(4)));

#define AS1 __attribute__((address_space(1)))
#define AS3 __attribute__((address_space(3)))

__device__ __forceinline__ void gload_lds16(const void* g, void* l) {
    __builtin_amdgcn_global_load_lds((AS1 void*)(g), (AS3 void*)(l), 16, 0, 0);
}

template <int N> __device__ __forceinline__ void vmwait() {
    asm volatile("s_waitcnt vmcnt(%0)" :: "n"(N) : "memory");
}

// fast transcendentals: v_exp_f32 (exp2) + v_rcp_f32, ~1 ulp, correct saturation
__device__ __forceinline__ float sigmoid_fast(float v) {
    return __builtin_amdgcn_rcpf(1.f + __builtin_amdgcn_exp2f(-1.44269504f * v));
}
__device__ __forceinline__ float tanh_fast(float v) {
    return 1.f - 2.f * __builtin_amdgcn_rcpf(1.f + __builtin_amdgcn_exp2f(2.88539008f * v));
}

// ---------------- fused LDS-tiled transpose+cast of W1|W3|W4|W5 -> WtQ[5120][256] ----------------
__global__ __launch_bounds__(256) void tposeq_kernel(
    const float* __restrict__ W1, const float* __restrict__ W3,
    const float* __restrict__ W4, const float* __restrict__ W5, f16* __restrict__ Wt) {
    __shared__ float T[64][65];
    const int y = blockIdx.y;
    const float* W; int nw, n0, orow;
    if (y < 32)      { W = W1; nw = 2048; n0 = y * 64;        orow = 0;    }
    else if (y < 48) { W = W3; nw = 1024; n0 = (y - 32) * 64; orow = 2048; }
    else if (y < 64) { W = W4; nw = 1024; n0 = (y - 48) * 64; orow = 3072; }
    else             { W = W5; nw = 1024; n0 = (y - 64) * 64; orow = 4096; }
    const int k0 = blockIdx.x * 64;
    const int tid = threadIdx.x;
    const int rr = tid >> 4, cc = (tid & 15) * 4;
#pragma unroll
    for (int p = 0; p < 4; ++p) {
        int k = rr + p * 16;
        float4 v = *(const float4*)&W[(size_t)(k0 + k) * nw + n0 + cc];
        T[k][cc] = v.x; T[k][cc + 1] = v.y; T[k][cc + 2] = v.z; T[k][cc + 3] = v.w;
    }
    __syncthreads();
#pragma unroll
    for (int p = 0; p < 4; ++p) {
        int n = rr + p * 16;
        f16x4 h;
        h[0] = (f16)T[cc][n]; h[1] = (f16)T[cc + 1][n];
        h[2] = (f16)T[cc + 2][n]; h[3] = (f16)T[cc + 3][n];
        *(f16x4*)&Wt[(size_t)(orow + n0 + n) * 256 + k0 + cc] = h;
    }
}

// ---------------- LDS-tiled transpose+cast: Wt[n][k] = (f16)W[k][n], 64x64 tiles (W2) ------------
__global__ __launch_bounds__(256) void tpose_kernel(const float* __restrict__ W, f16* __restrict__ Wt,
                                                    int K, int N) {
    __shared__ float T[64][65];
    const int k0 = blockIdx.x * 64, n0 = blockIdx.y * 64;
    const int tid = threadIdx.x;
    const int rr = tid >> 4, cc = (tid & 15) * 4;
#pragma unroll
    for (int p = 0; p < 4; ++p) {
        int k = rr + p * 16;
        float4 v = *(const float4*)&W[(size_t)(k0 + k) * N + n0 + cc];
        T[k][cc] = v.x; T[k][cc + 1] = v.y; T[k][cc + 2] = v.z; T[k][cc + 3] = v.w;
    }
    __syncthreads();
#pragma unroll
    for (int p = 0; p < 4; ++p) {
        int n = rr + p * 16;
        f16x4 h;
        h[0] = (f16)T[cc][n]; h[1] = (f16)T[cc + 1][n];
        h[2] = (f16)T[cc + 2][n]; h[3] = (f16)T[cc + 3][n];
        *(f16x4*)&Wt[(size_t)(n0 + n) * K + k0 + cc] = h;
    }
}

// ---------------- embedding cast to f16, padded rows zeroed ----------------
__global__ __launch_bounds__(256) void ecast_kernel(const float* __restrict__ emb, f16* __restrict__ E) {
    int r = blockIdx.x * 4 + (threadIdx.x >> 6);
    int c = (threadIdx.x & 63) * 4;
    float4 v = make_float4(0.f, 0.f, 0.f, 0.f);
    if (r < 10000) v = *(const float4*)&emb[(size_t)r * 256 + c];
    f16x4 h;
    h[0] = (f16)v.x; h[1] = (f16)v.y; h[2] = (f16)v.z; h[3] = (f16)v.w;
    *(f16x4*)&E[(size_t)r * 256 + c] = h;
}

// ---------------- GEMM 0: 160x256 tile, BK=32, K=256, TRIPLE-buffer distance-2 pipeline ----------
// Per iter: stage(t+2) -> sbuf; ds_read tile t; setprio-wrapped 20 MFMA; counted vmcnt (allow only
// t+2's loads outstanding: wave-exact 4 (waves 0-1, extra A chunk) / 3) ; ONE raw s_barrier.
// Loads never drain to 0 mid-loop (~2 iters of latency cover). Each wave's vmcnt retires its own
// tile-t+1 chunks pre-barrier => post-barrier ALL waves' chunks landed. Skew <1 iter => the buffer
// staged at iter t (t+2 === t-1 mod 3) was fully read. LDS 80 KB (3x26KB bufs + Cs overlay) = 2/CU.
__global__ __launch_bounds__(512, 4) void gemm0_kernel(
    const f16* __restrict__ A, const f16* __restrict__ Bt,
    const float* __restrict__ bb1, const float* __restrict__ bb3, const float* __restrict__ bb4,
    f16* __restrict__ O0, f16* __restrict__ O1, f16* __restrict__ O3) {
    constexpr int BK = 32, SMASK = 3, RSH = 1;
    constexpr int ABUF = 160 * BK, BBUF = 256 * BK, BUFSZ = ABUF + BBUF;  // 13312 f16
    constexpr int CT = 20;
    __shared__ __align__(16) f16 SM[40960];   // 80 KB: 3 bufs (39936) | Cs overlay (40960)
    f16* Cs = SM;
    // bijective XCD remap (m204), row-major decode
    const int nwg = gridDim.x, orig = blockIdx.x;
    const int q = nwg >> 3, rm = nwg & 7;
    const int xcd = orig & 7, loc = orig >> 3;
    const int wg = (xcd < rm ? xcd * (q + 1) : rm * (q + 1) + (xcd - rm) * q) + loc;
    const int rowT = wg / CT, colT = wg - rowT * CT;
    const int row0 = rowT * 160, col0 = colT * 256;

    const int tid = threadIdx.x;
    const int wave = tid >> 6, lane = tid & 63;
    const int wr = wave >> 2, wc = wave & 3;
    const int lo16 = lane & 15, hi4 = lane >> 4;
    const bool hv = (wave < 2);                // waves 0-1 carry the extra A chunk

    const bool PM = (col0 >= 2048) && (col0 < 4096);

    f32x4 acc[5][4] = {};

    // hoisted k0-invariant staging sources
    const f16* aptr[2]; int adst[2];
    const f16* bptr[2]; int bdst[2];
#pragma unroll
    for (int it = 0; it < 2; ++it) {
        int c = it * 512 + tid;
        int r = c >> 2, sl = c & 3;
        int kc = (sl ^ ((r >> RSH) & SMASK)) << 3;   // pre-swizzled source (rule #21)
        aptr[it] = A + (size_t)(row0 + (r < 160 ? r : 0)) * 256 + kc;
        adst[it] = c * 8;
    }
#pragma unroll
    for (int it = 0; it < 2; ++it) {
        int c = it * 512 + tid;
        int r = c >> 2, sl = c & 3;
        int kc = (sl ^ ((r >> RSH) & SMASK)) << 3;
        int brow = col0 + r;
        if (PM) {                                    // W3/W4 16-col interleave remap
            int qc = col0 - 2048 + r;
            int grp = qc >> 5, q2 = qc & 31;
            brow = (q2 < 16) ? (2048 + grp * 16 + q2) : (3072 + grp * 16 + (q2 - 16));
        }
        bptr[it] = Bt + (size_t)brow * 256 + kc;
        bdst[it] = c * 8;
    }

    auto stage = [&](int buf, int k0) {
        f16* As = SM + buf * BUFSZ;
        f16* Bs = As + ABUF;
        gload_lds16(aptr[0] + k0, &As[adst[0]]);
        if (tid < 128) gload_lds16(aptr[1] + k0, &As[adst[1]]);
        gload_lds16(bptr[0] + k0, &Bs[bdst[0]]);
        gload_lds16(bptr[1] + k0, &Bs[bdst[1]]);
    };

    stage(0, 0);
    stage(1, 32);
    if (hv) vmwait<4>(); else vmwait<3>();     // tile 0 landed (tile 1 in flight)
    __builtin_amdgcn_s_barrier();

    int rbuf = 0, sbuf = 2;
    for (int t = 0; t < 8; ++t) {
        if (t + 2 < 8) stage(sbuf, (t + 2) * 32);
        const f16* As = SM + rbuf * BUFSZ;
        const f16* Bs = As + ABUF;
        f16x8 af[5], bf[4];
#pragma unroll
        for (int m = 0; m < 5; ++m) {
            int row = wr * 80 + m * 16 + lo16;
            af[m] = *(const f16x8*)&As[row * BK + ((hi4 ^ ((row >> RSH) & SMASK)) << 3)];
        }
#pragma unroll
        for (int n = 0; n < 4; ++n) {
            int row = wc * 64 + n * 16 + lo16;
            bf[n] = *(const f16x8*)&Bs[row * BK + ((hi4 ^ ((row >> RSH) & SMASK)) << 3)];
        }
        __builtin_amdgcn_s_setprio(1);
#pragma unroll
        for (int m = 0; m < 5; ++m)
#pragma unroll
            for (int n = 0; n < 4; ++n)
                acc[m][n] = __builtin_amdgcn_mfma_f32_16x16x32_f16(af[m], bf[n], acc[m][n], 0, 0, 0);
        __builtin_amdgcn_s_setprio(0);
        if (t + 1 < 8) {
            if (t + 2 < 8) { if (hv) vmwait<4>(); else vmwait<3>(); }
            else vmwait<0>();
        }
        __builtin_amdgcn_s_barrier();
        rbuf = (rbuf == 2) ? 0 : rbuf + 1;
        sbuf = (sbuf == 2) ? 0 : sbuf + 1;
    }

    if (PM) {
        // p = sigmoid(acc_even + b3) * tanh(acc_odd + b4) -> 160x128 Pt tile
        const int pcol0 = (col0 - 2048) >> 1;
#pragma unroll
        for (int p = 0; p < 2; ++p) {
            int colP = wc * 32 + p * 16 + lo16;
            float bi = bb3[pcol0 + colP], bg = bb4[pcol0 + colP];
            int ch = colP >> 3, el = colP & 7;
#pragma unroll
            for (int m = 0; m < 5; ++m)
#pragma unroll
                for (int j = 0; j < 4; ++j) {
                    int row = wr * 80 + m * 16 + hi4 * 4 + j;
                    float pi = sigmoid_fast(acc[m][2 * p][j] + bi);
                    float pg = tanh_fast(acc[m][2 * p + 1][j] + bg);
                    Cs[row * 128 + ((ch ^ (row & 15)) << 3) + el] = (f16)(pi * pg);
                }
        }
        __syncthreads();
#pragma unroll
        for (int it = 0; it < 5; ++it) {
            int idx = it * 512 + tid;
            int row = idx >> 4, ch = idx & 15;
            f16x8 v = *(const f16x8*)&Cs[row * 128 + ((ch ^ (row & 15)) << 3)];
            *(f16x8*)&O1[(size_t)(row0 + row) * 1024 + pcol0 + ch * 8] = v;
        }
        return;
    }

    f16* Oe; size_t ostr; const float* bp;
    if (col0 < 2048) { Oe = O0 + col0;          ostr = 2048; bp = bb1 + col0; }
    else             { Oe = O3 + (col0 - 4096); ostr = 1024; bp = nullptr;    }

#pragma unroll
    for (int n = 0; n < 4; ++n) {
        int col = wc * 64 + n * 16 + lo16;
        float b = bp ? bp[col] : 0.f;
        int ch = col >> 3, el = col & 7;
#pragma unroll
        for (int m = 0; m < 5; ++m)
#pragma unroll
            for (int j = 0; j < 4; ++j) {
                int row = wr * 80 + m * 16 + hi4 * 4 + j;
                Cs[row * 256 + ((ch ^ (row & 31)) << 3) + el] = (f16)fmaxf(acc[m][n][j] + b, 0.f);
            }
    }
    __syncthreads();
#pragma unroll
    for (int it = 0; it < 10; ++it) {
        int idx = it * 512 + tid;
        int row = idx >> 5, ch = idx & 31;
        f16x8 v = *(const f16x8*)&Cs[row * 256 + ((ch ^ (row & 31)) << 3)];
        *(f16x8*)&Oe[(size_t)(row0 + row) * ostr + ch * 8] = v;
    }
}

// ---------------- GEMM 1: Mt = tanh(Rb @ W2t^T + b2), 160x128 tile, BK=32, K=2048 ----------------
// Same triple-buffer distance-2 counted-vmcnt pipeline; nt=64 gives a long steady state.
// LDS 54 KB (3 x 18 KB bufs, Cs 40 KB overlay) -> 2 blocks/CU. Grid 64x8 = 512.
__global__ __launch_bounds__(512, 4) void gemm1_kernel(
    const f16* __restrict__ A, const f16* __restrict__ Bt,
    const float* __restrict__ bb2, f16* __restrict__ O0) {
    constexpr int BK = 32, SMASK = 3, RSH = 1;
    constexpr int ABUF = 160 * BK, BBUF = 128 * BK, BUFSZ = ABUF + BBUF;  // 9216 f16
    constexpr int CT = 8;
    __shared__ __align__(16) f16 SM[27648];   // 54 KB: 3 bufs; Cs overlay (20480 f16)
    f16* Cs = SM;
    const int nwg = gridDim.x, orig = blockIdx.x;
    const int q = nwg >> 3, rm = nwg & 7;
    const int xcd = orig & 7, loc = orig >> 3;
    const int wg = (xcd < rm ? xcd * (q + 1) : rm * (q + 1) + (xcd - rm) * q) + loc;
    const int rowT = wg / CT, colT = wg - rowT * CT;
    const int row0 = rowT * 160, col0 = colT * 128;

    const int tid = threadIdx.x;
    const int wave = tid >> 6, lane = tid & 63;
    const int wr = wave >> 2, wc = wave & 3;
    const int lo16 = lane & 15, hi4 = lane >> 4;
    const bool hv = (wave < 2);

    f32x4 acc[5][2] = {};

    const f16* aptr[2]; int adst[2];
    const f16* bptr0; int bdst0;
#pragma unroll
    for (int it = 0; it < 2; ++it) {
        int c = it * 512 + tid;
        int r = c >> 2, sl = c & 3;
        int kc = (sl ^ ((r >> RSH) & SMASK)) << 3;
        aptr[it] = A + (size_t)(row0 + (r < 160 ? r : 0)) * 2048 + kc;
        adst[it] = c * 8;
    }
    {
        int c = tid;
        int r = c >> 2, sl = c & 3;
        int kc = (sl ^ ((r >> RSH) & SMASK)) << 3;
        bptr0 = Bt + (size_t)(col0 + r) * 2048 + kc;
        bdst0 = c * 8;
    }

    auto stage = [&](int buf, int k0) {
        f16* As = SM + buf * BUFSZ;
        f16* Bs = As + ABUF;
        gload_lds16(aptr[0] + k0, &As[adst[0]]);
        if (tid < 128) gload_lds16(aptr[1] + k0, &As[adst[1]]);
        gload_lds16(bptr0 + k0, &Bs[bdst0]);
    };

    stage(0, 0);
    stage(1, 32);
    if (hv) vmwait<3>(); else vmwait<2>();
    __builtin_amdgcn_s_barrier();

    int rbuf = 0, sbuf = 2;
    for (int t = 0; t < 64; ++t) {
        if (t + 2 < 64) stage(sbuf, (t + 2) * 32);
        const f16* As = SM + rbuf * BUFSZ;
        const f16* Bs = As + ABUF;
        f16x8 af[5], bf[2];
#pragma unroll
        for (int m = 0; m < 5; ++m) {
            int row = wr * 80 + m * 16 + lo16;
            af[m] = *(const f16x8*)&As[row * BK + ((hi4 ^ ((row >> RSH) & SMASK)) << 3)];
        }
#pragma unroll
        for (int n = 0; n < 2; ++n) {
            int row = wc * 32 + n * 16 + lo16;
            bf[n] = *(const f16x8*)&Bs[row * BK + ((hi4 ^ ((row >> RSH) & SMASK)) << 3)];
        }
        __builtin_amdgcn_s_setprio(1);
#pragma unroll
        for (int m = 0; m < 5; ++m)
#pragma unroll
            for (int n = 0; n < 2; ++n)
                acc[m][n] = __builtin_amdgcn_mfma_f32_16x16x32_f16(af[m], bf[n], acc[m][n], 0, 0, 0);
        __builtin_amdgcn_s_setprio(0);
        if (t + 1 < 64) {
            if (t + 2 < 64) { if (hv) vmwait<3>(); else vmwait<2>(); }
            else vmwait<0>();
        }
        __builtin_amdgcn_s_barrier();
        rbuf = (rbuf == 2) ? 0 : rbuf + 1;
        sbuf = (sbuf == 2) ? 0 : sbuf + 1;
    }

    // tanh+bias epilogue -> 160x128 tile of O0 (stride 1024)
    const float* bp = bb2 + col0;
#pragma unroll
    for (int n = 0; n < 2; ++n) {
        int col = wc * 32 + n * 16 + lo16;
        float b = bp[col];
        int ch = col >> 3, el = col & 7;
#pragma unroll
        for (int m = 0; m < 5; ++m)
#pragma unroll
            for (int j = 0; j < 4; ++j) {
                int row = wr * 80 + m * 16 + hi4 * 4 + j;
                Cs[row * 128 + ((ch ^ (row & 15)) << 3) + el] = (f16)tanh_fast(acc[m][n][j] + b);
            }
    }
    __syncthreads();
#pragma unroll
    for (int it = 0; it < 5; ++it) {
        int idx = it * 512 + tid;
        int row = idx >> 4, ch = idx & 15;
        f16x8 v = *(const f16x8*)&Cs[row * 128 + ((ch ^ (row & 15)) << 3)];
        *(f16x8*)&O0[(size_t)(row0 + row) * 1024 + col0 + ch * 8] = v;
    }
}

// ---------------- scan over T, XCD-sliced: block = (batch b, unit-slice x of 128) ----------------
// blockIdx = b*8 + x -> round-robin dispatch pins slice x to XCD x (L2 affinity).
// 32-slot / 20-deep static software pipeline: 60 loads in flight (vmcnt cap 63).
__global__ __launch_bounds__(64) void scan_slice_kernel(
    const int* __restrict__ tokens, const f16* __restrict__ Mt, const f16* __restrict__ Pt,
    const f16* __restrict__ Ut, const float* __restrict__ state0,
    const float* __restrict__ Wout, float* __restrict__ partial) {
    __shared__ int toks[288];
    const int bid = blockIdx.x;
    const int b = bid >> 3, x = bid & 7;
    const int lane = threadIdx.x;
    for (int t = lane; t < 288; t += 64) toks[t] = (t < 250) ? tokens[b * 250 + t] : 0;
    __syncthreads();

    const int u0 = x * 128 + lane * 2;
    float2 sv = *(const float2*)&state0[(size_t)b * 1024 + u0];
    float s0 = sv.x, s1 = sv.y;

    f16x2 m[32], p[32], u[32];
#pragma unroll
    for (int k = 0; k < 20; ++k) {
        size_t nb = (size_t)toks[k] * 1024 + u0;
        m[k] = *(const f16x2*)&Mt[nb];
        p[k] = *(const f16x2*)&Pt[nb];
        u[k] = *(const f16x2*)&Ut[nb];
    }

    for (int tb = 0; tb < 224; tb += 32) {
#pragma unroll
        for (int k = 0; k < 32; ++k) {
            const int ls = (k + 20) & 31;
            size_t nb = (size_t)toks[tb + k + 20] * 1024 + u0;
            m[ls] = *(const f16x2*)&Mt[nb];
            p[ls] = *(const f16x2*)&Pt[nb];
            u[ls] = *(const f16x2*)&Ut[nb];
            float y0 = fmaxf((float)m[k][0] * s0 + (float)p[k][0], 0.f);
            s0 = fmaxf((float)u[k][0] + y0, 0.f);
            float y1 = fmaxf((float)m[k][1] * s1 + (float)p[k][1], 0.f);
            s1 = fmaxf((float)u[k][1] + y1, 0.f);
        }
    }
#pragma unroll
    for (int k = 0; k < 26; ++k) {
        if (k < 6) {
            const int ls = k + 20;
            size_t nb = (size_t)toks[244 + k] * 1024 + u0;
            m[ls] = *(const f16x2*)&Mt[nb];
            p[ls] = *(const f16x2*)&Pt[nb];
            u[ls] = *(const f16x2*)&Ut[nb];
        }
        float y0 = fmaxf((float)m[k][0] * s0 + (float)p[k][0], 0.f);
        s0 = fmaxf((float)u[k][0] + y0, 0.f);
        float y1 = fmaxf((float)m[k][1] * s1 + (float)p[k][1], 0.f);
        s1 = fmaxf((float)u[k][1] + y1, 0.f);
    }

    float2 wv = *(const float2*)&Wout[u0];
    float part = s0 * wv.x + s1 * wv.y;
#pragma unroll
    for (int o = 32; o > 0; o >>= 1) part += __shfl_down(part, o, 64);
    if (lane == 0) partial[bid] = part;
}

// ---------------- final reduce: out[b] = sigmoid(sum_x partial[b*8+x] + bout) ----------------
__global__ __launch_bounds__(256) void final_kernel(const float* __restrict__ partial,
                                                    const float* __restrict__ bout,
                                                    float* __restrict__ out) {
    int b = threadIdx.x;
    float tot = bout[0];
#pragma unroll
    for (int w = 0; w < 8; ++w) tot += partial[b * 8 + w];
    out[b] = sigmoid_fast(tot);
}

extern "C" void kernel_launch(void* const* d_in, const int* in_sizes, int n_in,
                              void* d_out, int out_size, void* d_ws, size_t ws_size,
                              hipStream_t stream) {
    const int*   tokens = (const int*)  d_in[0];
    const float* emb    = (const float*)d_in[1];
    const float* W1     = (const float*)d_in[2];
    const float* b1     = (const float*)d_in[3];
    const float* W2     = (const float*)d_in[4];
    const float* b2     = (const float*)d_in[5];
    const float* W3     = (const float*)d_in[6];
    const float* b3     = (const float*)d_in[7];
    const float* W4     = (const float*)d_in[8];
    const float* b4     = (const float*)d_in[9];
    const float* W5     = (const float*)d_in[10];
    const float* Wout   = (const float*)d_in[11];
    const float* bout   = (const float*)d_in[12];
    const float* state0 = (const float*)d_in[13];
    float* out = (float*)d_out;

    const int RP = 10240;  // padded vocab rows: 64 x 160 (gemm M-tiles)

    char* ws = (char*)d_ws;
    size_t off = 0;
    auto alloc = [&](size_t bytes) -> void* {
        void* p = ws + off;
        off += (bytes + 255) & ~(size_t)255;
        return p;
    };
    f16* WtQ = (f16*)alloc((size_t)5120 * 256 * 2);   // W1|W3|W4|W5 transposed [5120][256]
    f16* Wt2 = (f16*)alloc((size_t)1024 * 2048 * 2);
    f16* E   = (f16*)alloc((size_t)RP * 256 * 2);
    f16* Rb  = (f16*)alloc((size_t)RP * 2048 * 2);
    f16* Mt  = (f16*)alloc((size_t)RP * 1024 * 2);
    f16* Pt  = (f16*)alloc((size_t)RP * 1024 * 2);
    f16* Ut  = (f16*)alloc((size_t)RP * 1024 * 2);
    float* partial = (float*)alloc((size_t)2048 * 4);
    (void)ws_size; (void)in_sizes; (void)n_in; (void)out_size;

    // weights -> f16 transposed [N][K]
    tposeq_kernel<<<dim3(4, 80), 256, 0, stream>>>(W1, W3, W4, W5, WtQ);
    tpose_kernel<<<dim3(32, 16), 256, 0, stream>>>(W2, Wt2, 2048, 1024);
    ecast_kernel<<<RP / 4, 256, 0, stream>>>(emb, E);

    // fused per-vocab tables: E @ [W1 | W3/W4 interleaved | W5]  (N=5120, K=256)
    gemm0_kernel<<<(RP / 160) * (5120 / 256), 512, 0, stream>>>(
        E, WtQ, b1, b3, b4, Rb, Pt, Ut);
    // Mt = tanh(relu(...) @ W2 + b2)  (N=1024, K=2048)
    gemm1_kernel<<<(RP / 160) * (1024 / 128), 512, 0, stream>>>(
        Rb, Wt2, b2, Mt);

    // scan (XCD-sliced, 20-deep pipelined) + final projection reduce
    scan_slice_kernel<<<2048, 64, 0, stream>>>(tokens, Mt, Pt, Ut, state0, Wout, partial);
    final_kernel<<<1, 256, 0, stream>>>(partial, bout, out);
}